// Round 8
// baseline (169.710 us; speedup 1.0000x reference)
//
#include <hip/hip_runtime.h>

// Problem constants (fixed by reference: B=64, T=1024, D=256)
constexpr int Bn = 64;
constexpr int Tn = 1024;
constexpr int Dn = 256;

constexpr int TPB  = 256;        // 4 waves per block, each wave fully independent
constexpr int NBLK = Tn / 4;     // one t per wave -> 256 blocks
constexpr int NBIN = 64;         // partial-sum bins

using short8 = __attribute__((ext_vector_type(8))) short;   // 8 bf16 — MFMA A/B frag
using f32x16 = __attribute__((ext_vector_type(16))) float;  // MFMA 32x32 accumulator

__device__ __forceinline__ float dot4(const float4& a, const float4& b) {
    return a.x * b.x + a.y * b.y + a.z * b.z + a.w * b.w;
}

// fp32 -> bf16 bits, round-to-nearest-even
__device__ __forceinline__ unsigned int bfbits(float x) {
    unsigned int u = __builtin_bit_cast(unsigned int, x);
    return (u + 0x7FFFu + ((u >> 16) & 1u)) >> 16;
}
__device__ __forceinline__ unsigned int pack_bf2(float lo, float hi) {
    return bfbits(lo) | (bfbits(hi) << 16);
}

// One K=16 chunk of fragments, statically addressed (rule #20): 32 VGPRs.
struct Ch { float4 v0[2], v1[2], a0[2], a1[2]; };

__global__ __launch_bounds__(TPB, 3)   // cap ~170 VGPR -> 3 blocks/CU (12 waves/CU)
void cmfm_main(const float* __restrict__ fv, const float* __restrict__ fa,
               const int* __restrict__ labels, float* __restrict__ acc)
{
    const int lane = threadIdx.x & 63;
    const int wave = threadIdx.x >> 6;
    const int t    = blockIdx.x * 4 + wave;    // each wave owns one timestep

    const int mrow = lane & 31;
    const int half = lane >> 5;

    // Direct global->register fragment pointers (MFMA A/B layout, validated r1-r7):
    // lane reads rows mrow and mrow+32, k-slice 8*half of each K=16 chunk.
    const size_t RS = (size_t)Tn * Dn;         // row stride in floats
    const float* pv0 = fv + ((size_t)mrow * Tn + t) * Dn + half * 8;
    const float* pv1 = pv0 + 32 * RS;
    const float* pa0 = fa + ((size_t)mrow * Tn + t) * Dn + half * 8;
    const float* pa1 = pa0 + 32 * RS;

    f32x16 C00, C01, C10, C11;                 // 64x64 output, 4 quadrant accumulators
    #pragma unroll
    for (int r = 0; r < 16; ++r) { C00[r] = 0.f; C01[r] = 0.f; C10[r] = 0.f; C11[r] = 0.f; }

    float sqv0 = 0.f, sqv1 = 0.f, sqa0 = 0.f, sqa1 = 0.f, dva0 = 0.f, dva1 = 0.f;

    #define LOADC(ch, OFF) do {                                              \
        ch.v0[0] = *reinterpret_cast<const float4*>(pv0 + (OFF));            \
        ch.v0[1] = *reinterpret_cast<const float4*>(pv0 + (OFF) + 4);        \
        ch.v1[0] = *reinterpret_cast<const float4*>(pv1 + (OFF));            \
        ch.v1[1] = *reinterpret_cast<const float4*>(pv1 + (OFF) + 4);        \
        ch.a0[0] = *reinterpret_cast<const float4*>(pa0 + (OFF));            \
        ch.a0[1] = *reinterpret_cast<const float4*>(pa0 + (OFF) + 4);        \
        ch.a1[0] = *reinterpret_cast<const float4*>(pa1 + (OFF));            \
        ch.a1[1] = *reinterpret_cast<const float4*>(pa1 + (OFF) + 4);        \
    } while (0)

    #define CONSUME(ch) do {                                                 \
        sqv0 += dot4(ch.v0[0], ch.v0[0]) + dot4(ch.v0[1], ch.v0[1]);         \
        sqv1 += dot4(ch.v1[0], ch.v1[0]) + dot4(ch.v1[1], ch.v1[1]);         \
        sqa0 += dot4(ch.a0[0], ch.a0[0]) + dot4(ch.a0[1], ch.a0[1]);         \
        sqa1 += dot4(ch.a1[0], ch.a1[0]) + dot4(ch.a1[1], ch.a1[1]);         \
        dva0 += dot4(ch.v0[0], ch.a0[0]) + dot4(ch.v0[1], ch.a0[1]);         \
        dva1 += dot4(ch.v1[0], ch.a1[0]) + dot4(ch.v1[1], ch.a1[1]);         \
        union { short8 s8; uint4 u4; } vf0, vf1, af0, af1;                   \
        vf0.u4.x = pack_bf2(ch.v0[0].x, ch.v0[0].y);                         \
        vf0.u4.y = pack_bf2(ch.v0[0].z, ch.v0[0].w);                         \
        vf0.u4.z = pack_bf2(ch.v0[1].x, ch.v0[1].y);                         \
        vf0.u4.w = pack_bf2(ch.v0[1].z, ch.v0[1].w);                         \
        vf1.u4.x = pack_bf2(ch.v1[0].x, ch.v1[0].y);                         \
        vf1.u4.y = pack_bf2(ch.v1[0].z, ch.v1[0].w);                         \
        vf1.u4.z = pack_bf2(ch.v1[1].x, ch.v1[1].y);                         \
        vf1.u4.w = pack_bf2(ch.v1[1].z, ch.v1[1].w);                         \
        af0.u4.x = pack_bf2(ch.a0[0].x, ch.a0[0].y);                         \
        af0.u4.y = pack_bf2(ch.a0[0].z, ch.a0[0].w);                         \
        af0.u4.z = pack_bf2(ch.a0[1].x, ch.a0[1].y);                         \
        af0.u4.w = pack_bf2(ch.a0[1].z, ch.a0[1].w);                         \
        af1.u4.x = pack_bf2(ch.a1[0].x, ch.a1[0].y);                         \
        af1.u4.y = pack_bf2(ch.a1[0].z, ch.a1[0].w);                         \
        af1.u4.z = pack_bf2(ch.a1[1].x, ch.a1[1].y);                         \
        af1.u4.w = pack_bf2(ch.a1[1].z, ch.a1[1].w);                         \
        C00 = __builtin_amdgcn_mfma_f32_32x32x16_bf16(vf0.s8, af0.s8, C00, 0, 0, 0); \
        C01 = __builtin_amdgcn_mfma_f32_32x32x16_bf16(vf0.s8, af1.s8, C01, 0, 0, 0); \
        C10 = __builtin_amdgcn_mfma_f32_32x32x16_bf16(vf1.s8, af0.s8, C10, 0, 0, 0); \
        C11 = __builtin_amdgcn_mfma_f32_32x32x16_bf16(vf1.s8, af1.s8, C11, 0, 0, 0); \
    } while (0)

    // Rolled pair-loop with two named chunk buffers: load-ahead-one, and the
    // backedge structurally caps scheduler hoisting at <=2 chunks (no r4 spill).
    Ch cA, cB;
    LOADC(cA, 0);
    #pragma unroll 1
    for (int c = 0; c < Dn / 16; c += 2) {
        LOADC(cB, (c + 1) * 16);               // in flight across CONSUME(cA)
        CONSUME(cA);
        if (c + 2 < Dn / 16) LOADC(cA, (c + 2) * 16);
        CONSUME(cB);
    }
    #undef LOADC
    #undef CONSUME

    // ---- row norms: halves hold disjoint k-subsets -> one cross-half combine ----
    sqv0 += __shfl_xor(sqv0, 32);  sqv1 += __shfl_xor(sqv1, 32);
    sqa0 += __shfl_xor(sqa0, 32);  sqa1 += __shfl_xor(sqa1, 32);
    dva0 += __shfl_xor(dva0, 32);  dva1 += __shfl_xor(dva1, 32);
    const float rv0 = 1.f / fmaxf(sqrtf(sqv0), 1e-8f);   // V row mrow
    const float rv1 = 1.f / fmaxf(sqrtf(sqv1), 1e-8f);   // V row mrow+32
    const float ra0 = 1.f / fmaxf(sqrtf(sqa0), 1e-8f);   // A row mrow
    const float ra1 = 1.f / fmaxf(sqrtf(sqa1), 1e-8f);   // A row mrow+32

    // ---- aligned-pair term: one lane (half==0) contributes rows mrow, mrow+32 ----
    float pos = 0.f, neg = 0.f;
    if (half == 0) {
        const float c0 = dva0 * rv0 * ra0;
        const float c1 = dva1 * rv1 * ra1;
        if (labels[mrow] == 0)      pos += 1.f - c0; else neg += c0;   // d = 1-cos / cos
        if (labels[mrow + 32] == 0) pos += 1.f - c1; else neg += c1;
    }

    // ---- cross term: scale rv_i * ra_j, drop the i==j diagonal ----
    // C/D mapping (m74/m101, validated r1-r7): col = lane&31,
    // row ri = (reg&3) + 8*(reg>>2) + 4*(lane>>5)
    float od = 0.f;
    #define TILE(Cxx, RV, RA, EXCL) do {                                     \
        _Pragma("unroll")                                                    \
        for (int r = 0; r < 16; ++r) {                                       \
            const int ri = (r & 3) + 8 * (r >> 2) + 4 * half;                \
            const float rvi = __shfl(RV, ri);                                \
            float cc = Cxx[r];                                               \
            if (EXCL && ri == mrow) cc = 0.f;                                \
            od += rvi * (RA) * cc;                                           \
        }                                                                    \
    } while (0)
    TILE(C00, rv0, ra0, true);     // rows 0-31  x cols 0-31  (diagonal)
    TILE(C01, rv0, ra1, false);    // rows 0-31  x cols 32-63
    TILE(C10, rv1, ra0, false);    // rows 32-63 x cols 0-31
    TILE(C11, rv1, ra1, true);     // rows 32-63 x cols 32-63 (diagonal)
    #undef TILE

    // ---- wave reduce + 3 atomics into this t's bin (no cross-wave sync needed) ----
    #pragma unroll
    for (int off = 1; off < 64; off <<= 1) {
        pos += __shfl_xor(pos, off);
        neg += __shfl_xor(neg, off);
        od  += __shfl_xor(od, off);
    }
    if (lane == 0) {
        float* bin = acc + (size_t)(t & (NBIN - 1)) * 4;
        atomicAdd(bin + 0, pos);
        atomicAdd(bin + 1, neg);
        atomicAdd(bin + 2, od);
    }
}

__global__ void cmfm_final(const int* __restrict__ labels, const float* __restrict__ acc,
                           float* __restrict__ out) {
    const int l = threadIdx.x;     // 64 threads = 64 bins = 64 labels
    float p = acc[l * 4 + 0];
    float n = acc[l * 4 + 1];
    float o = acc[l * 4 + 2];
    float npf = (labels[l] == 0) ? 1.f : 0.f;
    #pragma unroll
    for (int off = 1; off < 64; off <<= 1) {
        p += __shfl_xor(p, off);
        n += __shfl_xor(n, off);
        o += __shfl_xor(o, off);
        npf += __shfl_xor(npf, off);
    }
    if (l == 0) {
        const int np = (int)(npf + 0.5f);
        const float cnt_pos = (float)np * (float)Tn;
        const float cnt_neg = (float)(Bn - np) * (float)Tn + (float)Bn * (float)(Bn - 1);
        float loss = 0.f;
        if (np > 0) loss += 2.0f * p / cnt_pos;                  // ALPHA
        loss += (2.0f * n + 1.0f * o / (float)Tn) / cnt_neg;     // BETA, GAMMA
        out[0] = loss;
    }
}

extern "C" void kernel_launch(void* const* d_in, const int* in_sizes, int n_in,
                              void* d_out, int out_size, void* d_ws, size_t ws_size,
                              hipStream_t stream) {
    const float* fv     = (const float*)d_in[0];
    const float* fa     = (const float*)d_in[1];
    const int*   labels = (const int*)d_in[2];
    float* acc = (float*)d_ws;        // 64 bins x {pos, neg, cross, pad}
    float* out = (float*)d_out;

    hipMemsetAsync(acc, 0, NBIN * 4 * sizeof(float), stream);
    cmfm_main<<<NBLK, TPB, 0, stream>>>(fv, fa, labels, acc);
    cmfm_final<<<1, 64, 0, stream>>>(labels, acc, out);
}